// Round 1
// baseline (41.620 us; speedup 1.0000x reference)
//
#include <hip/hip_runtime.h>
#include <math.h>

// AtomDistances: out[b,i,j] = mask[b,i]&&mask[b,j]&&(i!=j)
//                  ? 1/(safe_norm(pos[b,nbr[b,i,j]] - pos[b,i]) + 1e-8) : 0
// B=4, A=2048. neighbors arrive as int32, mask as int32 (0/1), per harness rules.

constexpr int A_DIM  = 2048;
constexpr int TI     = 8;     // output rows per block
constexpr int NTHR   = 256;   // 8 lane-groups of 32

__global__ __launch_bounds__(NTHR) void atom_distances_kernel(
    const float* __restrict__ pos,    // [B, A, 3]
    const int*   __restrict__ nbr,    // [B, A, A]
    const int*   __restrict__ mask,   // [B, A]
    float*       __restrict__ out) {  // [B, A, A]
  __shared__ float4 spos[A_DIM];   // 32 KB: xyz + pad, conflict-friendlier b128 reads
  __shared__ float  smask[A_DIM];  // 8 KB: 0.0 / 1.0

  const int rows_per_b = A_DIM / TI;             // 256
  const int b  = blockIdx.x / rows_per_b;
  const int i0 = (blockIdx.x % rows_per_b) * TI;

  const float* posb  = pos  + (size_t)b * A_DIM * 3;
  const int*   maskb = mask + (size_t)b * A_DIM;

  // Stage this batch's positions + mask into LDS (24 KB + 8 KB from L2).
  for (int t = threadIdx.x; t < A_DIM; t += NTHR) {
    float x = posb[3 * t + 0];
    float y = posb[3 * t + 1];
    float z = posb[3 * t + 2];
    spos[t]  = make_float4(x, y, z, 0.0f);
    smask[t] = maskb[t] ? 1.0f : 0.0f;
  }
  __syncthreads();

  const int il = threadIdx.x >> 5;   // 0..7 : which output row
  const int jt = threadIdx.x & 31;   // 0..31: lane within row-group
  const int i  = i0 + il;

  const float4 pi = spos[i];
  const float  mi = smask[i];

  const int*  nrow = nbr + ((size_t)b * A_DIM + i) * A_DIM;
  float*      orow = out + ((size_t)b * A_DIM + i) * A_DIM;

  // 2048 columns / (32 lanes * 4 per lane) = 16 chunks
  #pragma unroll 4
  for (int c = 0; c < A_DIM / (32 * 4); ++c) {
    const int j = (c * 32 + jt) * 4;
    const int4 n = *reinterpret_cast<const int4*>(nrow + j);

    float4 r;
    {
      const float4 p = spos[n.x & (A_DIM - 1)];
      const float dx = p.x - pi.x, dy = p.y - pi.y, dz = p.z - pi.z;
      const float d2 = dx * dx + dy * dy + dz * dz;
      const float d  = d2 > 0.0f ? sqrtf(d2) : 0.0f;
      const float m  = mi * smask[j + 0] * ((i != j + 0) ? 1.0f : 0.0f);
      r.x = m / (d + 1e-8f);
    }
    {
      const float4 p = spos[n.y & (A_DIM - 1)];
      const float dx = p.x - pi.x, dy = p.y - pi.y, dz = p.z - pi.z;
      const float d2 = dx * dx + dy * dy + dz * dz;
      const float d  = d2 > 0.0f ? sqrtf(d2) : 0.0f;
      const float m  = mi * smask[j + 1] * ((i != j + 1) ? 1.0f : 0.0f);
      r.y = m / (d + 1e-8f);
    }
    {
      const float4 p = spos[n.z & (A_DIM - 1)];
      const float dx = p.x - pi.x, dy = p.y - pi.y, dz = p.z - pi.z;
      const float d2 = dx * dx + dy * dy + dz * dz;
      const float d  = d2 > 0.0f ? sqrtf(d2) : 0.0f;
      const float m  = mi * smask[j + 2] * ((i != j + 2) ? 1.0f : 0.0f);
      r.z = m / (d + 1e-8f);
    }
    {
      const float4 p = spos[n.w & (A_DIM - 1)];
      const float dx = p.x - pi.x, dy = p.y - pi.y, dz = p.z - pi.z;
      const float d2 = dx * dx + dy * dy + dz * dz;
      const float d  = d2 > 0.0f ? sqrtf(d2) : 0.0f;
      const float m  = mi * smask[j + 3] * ((i != j + 3) ? 1.0f : 0.0f);
      r.w = m / (d + 1e-8f);
    }

    *reinterpret_cast<float4*>(orow + j) = r;
  }
}

extern "C" void kernel_launch(void* const* d_in, const int* in_sizes, int n_in,
                              void* d_out, int out_size, void* d_ws, size_t ws_size,
                              hipStream_t stream) {
  const float* pos  = (const float*)d_in[0];  // [4,2048,3] f32
  const int*   nbr  = (const int*)d_in[1];    // [4,2048,2048] int32
  const int*   mask = (const int*)d_in[2];    // [4,2048] int32 (bool)
  float*       out  = (float*)d_out;          // [4,2048,2048] f32

  const int B = in_sizes[2] / A_DIM;          // 4
  const int grid = B * (A_DIM / TI);          // 1024 blocks

  atom_distances_kernel<<<grid, NTHR, 0, stream>>>(pos, nbr, mask, out);
}

// Round 2
// 24.463 us; speedup vs baseline: 1.7013x; 1.7013x over previous
//
#include <hip/hip_runtime.h>

// AtomDistances: out[b,i,j] = mask[b,i]&&mask[b,j]&&(i!=j)
//                  ? 1/(safe_norm(pos[b,nbr[b,i,j]] - pos[b,i]) + 1e-8) : 0
// B=4, A=2048. neighbors int32, mask int32 (0/1).
//
// Structure: 512-thread blocks (8 waves), ONE ROW PER WAVE (wave-uniform
// masked-row skip: ~50% of rows are all-zero -> store zeros, no gathers).
// LDS: SoA float x/y/z (24 KB, b32 gathers over all 32 banks) + mask bits
// (256 B). ~24.3 KB/block -> 4 blocks/CU x 8 waves = 32 waves/CU.

constexpr int A_DIM = 2048;
constexpr int WPB   = 8;          // waves per block = rows per block
constexpr int NTHR  = WPB * 64;   // 512

__global__ __launch_bounds__(NTHR, 8) void atom_distances_kernel(
    const float* __restrict__ pos,    // [B, A, 3]
    const int*   __restrict__ nbr,    // [B, A, A]
    const int*   __restrict__ mask,   // [B, A]
    float*       __restrict__ out) {  // [B, A, A]
  __shared__ float    sxyz[3 * A_DIM];      // [x[2048], y[2048], z[2048]]
  __shared__ unsigned smaskbits[A_DIM / 32]; // 64 words

  const int blocks_per_b = A_DIM / WPB;     // 256
  const int b  = blockIdx.x / blocks_per_b;
  const int i0 = (blockIdx.x % blocks_per_b) * WPB;

  const float* posb  = pos  + (size_t)b * A_DIM * 3;
  const int*   maskb = mask + (size_t)b * A_DIM;

  // --- stage positions (SoA) + mask bits (ballot) ---
  for (int t = threadIdx.x; t < A_DIM; t += NTHR) {
    sxyz[t]             = posb[3 * t + 0];
    sxyz[t + A_DIM]     = posb[3 * t + 1];
    sxyz[t + 2 * A_DIM] = posb[3 * t + 2];
  }
  for (int r = 0; r < A_DIM / NTHR; ++r) {  // 4 rounds
    const int t = r * NTHR + threadIdx.x;
    const unsigned long long bal = __ballot(maskb[t] != 0);
    if ((threadIdx.x & 63) == 0) {
      const int wbase = t >> 5;             // lane0: even word index
      smaskbits[wbase]     = (unsigned)bal;
      smaskbits[wbase + 1] = (unsigned)(bal >> 32);
    }
  }
  __syncthreads();

  const int w    = threadIdx.x >> 6;   // wave id = row within block
  const int lane = threadIdx.x & 63;
  const int i    = i0 + w;

  float* orow = out + ((size_t)b * A_DIM + i) * A_DIM;

  const unsigned mi = (smaskbits[i >> 5] >> (i & 31)) & 1u;

  if (mi == 0) {
    // whole row masked out -> zeros (wave-uniform branch)
    const float4 z = make_float4(0.f, 0.f, 0.f, 0.f);
    #pragma unroll
    for (int c = 0; c < A_DIM / (64 * 4); ++c) {
      const int j0 = (c * 64 + lane) * 4;
      *reinterpret_cast<float4*>(orow + j0) = z;
    }
    return;
  }

  const float pix = sxyz[i];
  const float piy = sxyz[i + A_DIM];
  const float piz = sxyz[i + 2 * A_DIM];

  const int* nrow = nbr + ((size_t)b * A_DIM + i) * A_DIM;

  #pragma unroll 2
  for (int c = 0; c < A_DIM / (64 * 4); ++c) {  // 8 chunks
    const int j0 = (c * 64 + lane) * 4;
    const int4 n = *reinterpret_cast<const int4*>(nrow + j0);

    // column-mask bits: word broadcast within each 8-lane group
    const unsigned wbits = smaskbits[c * 8 + (lane >> 3)];
    const int bit = (lane & 7) * 4;

    float4 r;
    {
      const int t = n.x & (A_DIM - 1);
      const float dx = sxyz[t] - pix, dy = sxyz[t + A_DIM] - piy, dz = sxyz[t + 2 * A_DIM] - piz;
      const float d  = __builtin_amdgcn_sqrtf(dx * dx + dy * dy + dz * dz);
      const float m  = (float)((wbits >> (bit + 0)) & 1u) * ((i != j0 + 0) ? 1.0f : 0.0f);
      r.x = m * __builtin_amdgcn_rcpf(d + 1e-8f);
    }
    {
      const int t = n.y & (A_DIM - 1);
      const float dx = sxyz[t] - pix, dy = sxyz[t + A_DIM] - piy, dz = sxyz[t + 2 * A_DIM] - piz;
      const float d  = __builtin_amdgcn_sqrtf(dx * dx + dy * dy + dz * dz);
      const float m  = (float)((wbits >> (bit + 1)) & 1u) * ((i != j0 + 1) ? 1.0f : 0.0f);
      r.y = m * __builtin_amdgcn_rcpf(d + 1e-8f);
    }
    {
      const int t = n.z & (A_DIM - 1);
      const float dx = sxyz[t] - pix, dy = sxyz[t + A_DIM] - piy, dz = sxyz[t + 2 * A_DIM] - piz;
      const float d  = __builtin_amdgcn_sqrtf(dx * dx + dy * dy + dz * dz);
      const float m  = (float)((wbits >> (bit + 2)) & 1u) * ((i != j0 + 2) ? 1.0f : 0.0f);
      r.z = m * __builtin_amdgcn_rcpf(d + 1e-8f);
    }
    {
      const int t = n.w & (A_DIM - 1);
      const float dx = sxyz[t] - pix, dy = sxyz[t + A_DIM] - piy, dz = sxyz[t + 2 * A_DIM] - piz;
      const float d  = __builtin_amdgcn_sqrtf(dx * dx + dy * dy + dz * dz);
      const float m  = (float)((wbits >> (bit + 3)) & 1u) * ((i != j0 + 3) ? 1.0f : 0.0f);
      r.w = m * __builtin_amdgcn_rcpf(d + 1e-8f);
    }

    *reinterpret_cast<float4*>(orow + j0) = r;
  }
}

extern "C" void kernel_launch(void* const* d_in, const int* in_sizes, int n_in,
                              void* d_out, int out_size, void* d_ws, size_t ws_size,
                              hipStream_t stream) {
  const float* pos  = (const float*)d_in[0];  // [4,2048,3] f32
  const int*   nbr  = (const int*)d_in[1];    // [4,2048,2048] int32
  const int*   mask = (const int*)d_in[2];    // [4,2048] int32 (bool)
  float*       out  = (float*)d_out;          // [4,2048,2048] f32

  const int B = in_sizes[2] / A_DIM;          // 4
  const int grid = B * (A_DIM / WPB);         // 1024 blocks

  atom_distances_kernel<<<grid, NTHR, 0, stream>>>(pos, nbr, mask, out);
}

// Round 3
// 22.540 us; speedup vs baseline: 1.8465x; 1.0853x over previous
//
#include <hip/hip_runtime.h>

// AtomDistances: out[b,i,j] = mask[b,i]&&mask[b,j]&&(i!=j)
//                  ? 1/(safe_norm(pos[b,nbr[b,i,j]] - pos[b,i]) + 1e-8) : 0
// B=4, A=2048.
//
// R3: depth-4 software-pipelined neighbor prefetch (latency-bound fix:
// 4 int4 in flight/wave x 8 waves = 32/SIMD vs 16 before), rsqrt fast path,
// nontemporal output stores. Structure otherwise as R2 (one row per wave,
// wave-uniform skip of masked rows, SoA LDS positions + mask bits).

typedef float f4 __attribute__((ext_vector_type(4)));

constexpr int A_DIM = 2048;
constexpr int WPB   = 8;          // rows (waves) per block
constexpr int NTHR  = WPB * 64;   // 512

__global__ __launch_bounds__(NTHR, 8) void atom_distances_kernel(
    const float* __restrict__ pos,    // [B, A, 3]
    const int*   __restrict__ nbr,    // [B, A, A]
    const int*   __restrict__ mask,   // [B, A]
    float*       __restrict__ out) {  // [B, A, A]
  __shared__ float    sxyz[3 * A_DIM];       // SoA x/y/z, 24 KB
  __shared__ unsigned smaskbits[A_DIM / 32]; // 256 B

  const int blocks_per_b = A_DIM / WPB;      // 256
  const int b  = blockIdx.x / blocks_per_b;
  const int i0 = (blockIdx.x % blocks_per_b) * WPB;

  const float* posb  = pos  + (size_t)b * A_DIM * 3;
  const int*   maskb = mask + (size_t)b * A_DIM;

  for (int t = threadIdx.x; t < A_DIM; t += NTHR) {
    sxyz[t]             = posb[3 * t + 0];
    sxyz[t + A_DIM]     = posb[3 * t + 1];
    sxyz[t + 2 * A_DIM] = posb[3 * t + 2];
  }
  for (int r = 0; r < A_DIM / NTHR; ++r) {   // 4 rounds
    const int t = r * NTHR + threadIdx.x;
    const unsigned long long bal = __ballot(maskb[t] != 0);
    if ((threadIdx.x & 63) == 0) {
      const int wbase = t >> 5;
      smaskbits[wbase]     = (unsigned)bal;
      smaskbits[wbase + 1] = (unsigned)(bal >> 32);
    }
  }
  __syncthreads();

  const int w    = threadIdx.x >> 6;
  const int lane = threadIdx.x & 63;
  const int i    = i0 + w;

  float* orow = out + ((size_t)b * A_DIM + i) * A_DIM;
  const unsigned mi = (smaskbits[i >> 5] >> (i & 31)) & 1u;

  if (mi == 0) {  // whole row masked -> zeros, wave exits early
    const f4 z = {0.f, 0.f, 0.f, 0.f};
    #pragma unroll
    for (int c = 0; c < 8; ++c)
      __builtin_nontemporal_store(z, reinterpret_cast<f4*>(orow + (c * 64 + lane) * 4));
    return;
  }

  const float pix = sxyz[i];
  const float piy = sxyz[i + A_DIM];
  const float piz = sxyz[i + 2 * A_DIM];

  const int* nrow = nbr + ((size_t)b * A_DIM + i) * A_DIM;

#define LDN(c) (*reinterpret_cast<const int4*>(nrow + ((c) * 64 + lane) * 4))

#define ELEM(nt_, e_, dst_) { \
    const int t_ = (nt_) & (A_DIM - 1); \
    const float dx_ = sxyz[t_] - pix; \
    const float dy_ = sxyz[t_ + A_DIM] - piy; \
    const float dz_ = sxyz[t_ + 2 * A_DIM] - piz; \
    const float d2_ = dx_ * dx_ + dy_ * dy_ + dz_ * dz_; \
    const float inv_ = d2_ > 0.0f ? __builtin_amdgcn_rsqf(d2_) : 1e8f; \
    dst_ = ((((wbits >> (bit + e_)) & 1u) != 0u) & (i != j0 + e_)) ? inv_ : 0.0f; }

#define PROC(c, n) { \
    const int j0 = ((c) * 64 + lane) * 4; \
    const unsigned wbits = smaskbits[(c) * 8 + (lane >> 3)]; \
    const int bit = (lane & 7) * 4; \
    f4 r; \
    ELEM(n.x, 0, r.x); \
    ELEM(n.y, 1, r.y); \
    ELEM(n.z, 2, r.z); \
    ELEM(n.w, 3, r.w); \
    __builtin_nontemporal_store(r, reinterpret_cast<f4*>(orow + j0)); }

  // depth-4 rotating prefetch: 4 neighbor int4 loads always in flight
  int4 n0 = LDN(0), n1 = LDN(1), n2 = LDN(2), n3 = LDN(3);
  PROC(0, n0); n0 = LDN(4);
  PROC(1, n1); n1 = LDN(5);
  PROC(2, n2); n2 = LDN(6);
  PROC(3, n3); n3 = LDN(7);
  PROC(4, n0);
  PROC(5, n1);
  PROC(6, n2);
  PROC(7, n3);

#undef PROC
#undef ELEM
#undef LDN
}

extern "C" void kernel_launch(void* const* d_in, const int* in_sizes, int n_in,
                              void* d_out, int out_size, void* d_ws, size_t ws_size,
                              hipStream_t stream) {
  const float* pos  = (const float*)d_in[0];  // [4,2048,3] f32
  const int*   nbr  = (const int*)d_in[1];    // [4,2048,2048] int32
  const int*   mask = (const int*)d_in[2];    // [4,2048] int32 (bool)
  float*       out  = (float*)d_out;          // [4,2048,2048] f32

  const int B = in_sizes[2] / A_DIM;          // 4
  const int grid = B * (A_DIM / WPB);         // 1024 blocks

  atom_distances_kernel<<<grid, NTHR, 0, stream>>>(pos, nbr, mask, out);
}